// Round 1
// baseline (2932.611 us; speedup 1.0000x reference)
//
#include <hip/hip_runtime.h>

// DirGCNConv on MI355X.
// out = 0.5*(A_norm @ x) @ W_src + 0.5*(A_norm^T @ x) @ W_dst + 0.5*(b_src+b_dst)
// Restructured: h = 0.5*x@W first (dense), then per-edge scatter of w_e*h[src]
// directly into out. Two direction passes share one h buffer in ws.

constexpr int N_NODES = 50000;
constexpr int N_EDGES = 800000;
constexpr int D = 128;

__global__ __launch_bounds__(256) void k_degree(const int* __restrict__ row,
                                                const int* __restrict__ col,
                                                float* __restrict__ deg_out,
                                                float* __restrict__ deg_in) {
    int e = blockIdx.x * 256 + threadIdx.x;
    if (e < N_EDGES) {
        atomicAdd(&deg_out[row[e]], 1.0f);
        atomicAdd(&deg_in[col[e]], 1.0f);
    }
}

__global__ __launch_bounds__(256) void k_dinv(float* __restrict__ deg_out,
                                              float* __restrict__ deg_in) {
    int i = blockIdx.x * 256 + threadIdx.x;
    if (i < N_NODES) {
        float a = deg_out[i];
        deg_out[i] = (a > 0.f) ? rsqrtf(a) : 0.f;
        float b = deg_in[i];
        deg_in[i] = (b > 0.f) ? rsqrtf(b) : 0.f;
    }
}

// h[n, :] = 0.5 * x[n, :] @ W   (M=50000, K=128, N=128, fp32 vector ALU)
// Block = 256 threads = 4 waves; tile = 32 nodes. Wave w handles 8 nodes,
// lane handles a column pair. x-tile staged in LDS (reads are wave-broadcast,
// conflict-free).
__global__ __launch_bounds__(256) void k_gemm(const float* __restrict__ x,
                                              const float* __restrict__ W,
                                              float* __restrict__ h) {
    __shared__ float xs[32 * 128];
    const int t = threadIdx.x;
    const int base = blockIdx.x * 32;

    // Stage 32x128 fp32 tile: 4096 floats = 256 threads * 4 float4
    #pragma unroll
    for (int i = 0; i < 4; ++i) {
        int flat = (i * 256 + t) * 4;            // float offset in tile
        int node = base + (flat >> 7);
        float4 v = make_float4(0.f, 0.f, 0.f, 0.f);
        if (node < N_NODES) v = *(const float4*)&x[node * D + (flat & 127)];
        *(float4*)&xs[flat] = v;
    }
    __syncthreads();

    const int wave = t >> 6;
    const int lane = t & 63;
    const int nrow0 = wave * 8;       // first node (in tile) for this wave
    const int jc = lane * 2;          // column pair

    float acc[8][2] = {};
    for (int k = 0; k < D; k += 2) {
        float2 w0 = *(const float2*)&W[k * D + jc];
        float2 w1 = *(const float2*)&W[(k + 1) * D + jc];
        #pragma unroll
        for (int i = 0; i < 8; ++i) {
            float2 xv = *(const float2*)&xs[(nrow0 + i) * D + k];  // wave-broadcast
            acc[i][0] += xv.x * w0.x + xv.y * w1.x;
            acc[i][1] += xv.x * w0.y + xv.y * w1.y;
        }
    }

    #pragma unroll
    for (int i = 0; i < 8; ++i) {
        int node = base + nrow0 + i;
        if (node < N_NODES) {
            float2 o = make_float2(0.5f * acc[i][0], 0.5f * acc[i][1]);
            *(float2*)&h[node * D + jc] = o;
        }
    }
}

__global__ __launch_bounds__(256) void k_bias(const float* __restrict__ b_src,
                                              const float* __restrict__ b_dst,
                                              float* __restrict__ out) {
    int tid = blockIdx.x * 256 + threadIdx.x;   // N_NODES*32 threads, float4 each
    if (tid >= N_NODES * 32) return;
    int n = tid >> 5;
    int j = (tid & 31) * 4;
    float4 a = *(const float4*)&b_src[j];
    float4 b = *(const float4*)&b_dst[j];
    float4 o = make_float4(0.5f * (a.x + b.x), 0.5f * (a.y + b.y),
                           0.5f * (a.z + b.z), 0.5f * (a.w + b.w));
    *(float4*)&out[n * D + j] = o;
}

// out[idx_dst[e], :] += (sc_dst[idx_dst[e]] * sc_src[idx_src[e]]) * h[idx_src[e], :]
// 32 lanes per edge, 4 dims (float4) per lane -> 4 fp32 atomics per lane.
__global__ __launch_bounds__(256) void k_scatter(const int* __restrict__ idx_dst,
                                                 const int* __restrict__ idx_src,
                                                 const float* __restrict__ sc_dst,
                                                 const float* __restrict__ sc_src,
                                                 const float* __restrict__ h,
                                                 float* __restrict__ out) {
    int tid = blockIdx.x * 256 + threadIdx.x;
    int e = tid >> 5;
    if (e >= N_EDGES) return;
    int d = (tid & 31) * 4;
    int a = idx_dst[e];                // 32-lane broadcast load
    int b = idx_src[e];
    float w = sc_dst[a] * sc_src[b];
    float4 hv = *(const float4*)&h[b * D + d];
    float* p = &out[a * D + d];
    atomicAdd(p + 0, w * hv.x);
    atomicAdd(p + 1, w * hv.y);
    atomicAdd(p + 2, w * hv.z);
    atomicAdd(p + 3, w * hv.w);
}

extern "C" void kernel_launch(void* const* d_in, const int* in_sizes, int n_in,
                              void* d_out, int out_size, void* d_ws, size_t ws_size,
                              hipStream_t stream) {
    const float* x     = (const float*)d_in[0];
    const int*   edges = (const int*)d_in[1];      // [2, E]: row then col
    const float* W_src = (const float*)d_in[2];
    const float* b_src = (const float*)d_in[3];
    const float* W_dst = (const float*)d_in[4];
    const float* b_dst = (const float*)d_in[5];
    float* out = (float*)d_out;

    const int* row = edges;
    const int* col = edges + N_EDGES;

    float* h       = (float*)d_ws;                 // N_NODES*D floats (25.6 MB)
    float* deg_out = h + (size_t)N_NODES * D;      // N_NODES floats
    float* deg_in  = deg_out + N_NODES;            // N_NODES floats

    // zero degree accumulators (ws is poisoned 0xAA every call)
    hipMemsetAsync(deg_out, 0, 2 * (size_t)N_NODES * sizeof(float), stream);

    const int gE  = (N_EDGES + 255) / 256;
    const int gN  = (N_NODES + 255) / 256;
    const int gT  = (N_NODES + 31) / 32;                 // gemm tiles
    const int gB  = (N_NODES * 32 + 255) / 256;          // bias
    const int gS  = (N_EDGES * 32) / 256;                // scatter (exact: 800k*32 % 256 == 0)

    k_degree<<<gE, 256, 0, stream>>>(row, col, deg_out, deg_in);
    k_dinv<<<gN, 256, 0, stream>>>(deg_out, deg_in);

    // bias init of out (before any scatter)
    k_bias<<<gB, 256, 0, stream>>>(b_src, b_dst, out);

    // forward direction: h = 0.5*x@W_src; out[row] += w_e * h[col]
    k_gemm<<<gT, 256, 0, stream>>>(x, W_src, h);
    k_scatter<<<gS, 256, 0, stream>>>(row, col, deg_out, deg_in, h, out);

    // backward direction: h = 0.5*x@W_dst; out[col] += w_e * h[row]
    k_gemm<<<gT, 256, 0, stream>>>(x, W_dst, h);
    k_scatter<<<gS, 256, 0, stream>>>(col, row, deg_in, deg_out, h, out);
}

// Round 3
// 586.311 us; speedup vs baseline: 5.0018x; 5.0018x over previous
//
#include <hip/hip_runtime.h>

// DirGCNConv on MI355X — round 2 (fixed compile: no trailing backslash in comments).
// out = 0.5*(A_norm @ x) @ W_src + 0.5*(A_norm^T @ x) @ W_dst + 0.5*(b_src+b_dst)
// h = 0.5*x@W first (dense), then CSR gather (no feature atomics):
//   build CSR by dst on device (degree -> scan -> fill), then one wave per
//   destination node accumulates sum_e sc_src[src]*h[src,:] in registers and
//   does a single non-atomic out += sc_dst[node]*acc.

constexpr int N_NODES = 50000;
constexpr int N_EDGES = 800000;
constexpr int D = 128;

// ---------- degree (int atomics) ----------
__global__ __launch_bounds__(256) void k_degree(const int* __restrict__ row,
                                                const int* __restrict__ col,
                                                int* __restrict__ deg_row,
                                                int* __restrict__ deg_col) {
    int e = blockIdx.x * 256 + threadIdx.x;
    if (e < N_EDGES) {
        atomicAdd(&deg_row[row[e]], 1);
        atomicAdd(&deg_col[col[e]], 1);
    }
}

// ---------- d^{-1/2} scales ----------
__global__ __launch_bounds__(256) void k_dinv(const int* __restrict__ deg_row,
                                              const int* __restrict__ deg_col,
                                              float* __restrict__ sc_row,
                                              float* __restrict__ sc_col) {
    int i = blockIdx.x * 256 + threadIdx.x;
    if (i < N_NODES) {
        int a = deg_row[i];
        sc_row[i] = (a > 0) ? rsqrtf((float)a) : 0.f;
        int b = deg_col[i];
        sc_col[i] = (b > 0) ? rsqrtf((float)b) : 0.f;
    }
}

// ---------- exclusive prefix scan (one block per array) ----------
__global__ __launch_bounds__(1024) void k_scan(const int* __restrict__ degA,
                                               int* __restrict__ ptrA,
                                               const int* __restrict__ degB,
                                               int* __restrict__ ptrB) {
    const int* deg = blockIdx.x ? degB : degA;
    int* ptr = blockIdx.x ? ptrB : ptrA;
    __shared__ int sums[1024];
    const int t = threadIdx.x;
    const int per = (N_NODES + 1023) / 1024;   // 49
    const int s0 = t * per;
    int local = 0;
    for (int i = 0; i < per; ++i) {
        int idx = s0 + i;
        if (idx < N_NODES) local += deg[idx];
    }
    sums[t] = local;
    __syncthreads();
    // Hillis-Steele inclusive scan (two-sync pattern)
    for (int off = 1; off < 1024; off <<= 1) {
        int v = (t >= off) ? sums[t - off] : 0;
        __syncthreads();
        sums[t] += v;
        __syncthreads();
    }
    int carry = (t > 0) ? sums[t - 1] : 0;     // exclusive prefix of segment
    for (int i = 0; i < per; ++i) {
        int idx = s0 + i;
        if (idx < N_NODES) { ptr[idx] = carry; carry += deg[idx]; }
    }
}

// ---------- CSR bucket fill (1.6M cheap position atomics) ----------
__global__ __launch_bounds__(256) void k_fill(const int* __restrict__ row,
                                              const int* __restrict__ col,
                                              const int* __restrict__ ptr_row,
                                              const int* __restrict__ ptr_col,
                                              int* __restrict__ fill_row,
                                              int* __restrict__ fill_col,
                                              int* __restrict__ adj_fwd,
                                              int* __restrict__ adj_bwd) {
    int e = blockIdx.x * 256 + threadIdx.x;
    if (e >= N_EDGES) return;
    int r = row[e], c = col[e];
    int p = atomicAdd(&fill_row[r], 1);
    adj_fwd[ptr_row[r] + p] = c;
    int q = atomicAdd(&fill_col[c], 1);
    adj_bwd[ptr_col[c] + q] = r;
}

// ---------- h = 0.5 * x @ W  (fp32 vector ALU, 32-node tiles) ----------
__global__ __launch_bounds__(256) void k_gemm(const float* __restrict__ x,
                                              const float* __restrict__ W,
                                              float* __restrict__ h) {
    __shared__ float xs[32 * 128];
    const int t = threadIdx.x;
    const int base = blockIdx.x * 32;

    #pragma unroll
    for (int i = 0; i < 4; ++i) {
        int flat = (i * 256 + t) * 4;
        int node = base + (flat >> 7);
        float4 v = make_float4(0.f, 0.f, 0.f, 0.f);
        if (node < N_NODES) v = *(const float4*)&x[node * D + (flat & 127)];
        *(float4*)&xs[flat] = v;
    }
    __syncthreads();

    const int wave = t >> 6;
    const int lane = t & 63;
    const int nrow0 = wave * 8;
    const int jc = lane * 2;

    float acc[8][2] = {};
    for (int k = 0; k < D; k += 2) {
        float2 w0 = *(const float2*)&W[k * D + jc];
        float2 w1 = *(const float2*)&W[(k + 1) * D + jc];
        #pragma unroll
        for (int i = 0; i < 8; ++i) {
            float2 xv = *(const float2*)&xs[(nrow0 + i) * D + k];
            acc[i][0] += xv.x * w0.x + xv.y * w1.x;
            acc[i][1] += xv.x * w0.y + xv.y * w1.y;
        }
    }

    #pragma unroll
    for (int i = 0; i < 8; ++i) {
        int node = base + nrow0 + i;
        if (node < N_NODES) {
            float2 o = make_float2(0.5f * acc[i][0], 0.5f * acc[i][1]);
            *(float2*)&h[node * D + jc] = o;
        }
    }
}

// ---------- out init: 0.5*(b_src+b_dst) broadcast ----------
__global__ __launch_bounds__(256) void k_bias(const float* __restrict__ b_src,
                                              const float* __restrict__ b_dst,
                                              float* __restrict__ out) {
    int tid = blockIdx.x * 256 + threadIdx.x;
    if (tid >= N_NODES * 32) return;
    int n = tid >> 5;
    int j = (tid & 31) * 4;
    float4 a = *(const float4*)&b_src[j];
    float4 b = *(const float4*)&b_dst[j];
    float4 o = make_float4(0.5f * (a.x + b.x), 0.5f * (a.y + b.y),
                           0.5f * (a.z + b.z), 0.5f * (a.w + b.w));
    *(float4*)&out[n * D + j] = o;
}

// ---------- gather: one wave per destination node ----------
// out[n,:] += sc_dst[n] * sum_{src in adj[ptr[n]..+deg[n]]} sc_src[src]*h[src,:]
__global__ __launch_bounds__(256) void k_gather(const int* __restrict__ ptr,
                                                const int* __restrict__ deg,
                                                const int* __restrict__ adj,
                                                const float* __restrict__ sc_dst,
                                                const float* __restrict__ sc_src,
                                                const float* __restrict__ h,
                                                float* __restrict__ out) {
    const int node = blockIdx.x * 4 + (threadIdx.x >> 6);   // grid exact: 12500*4
    const int lane = threadIdx.x & 63;
    const int j = lane * 2;
    const int start = ptr[node];
    const int n = deg[node];

    float2 acc = make_float2(0.f, 0.f);
    for (int i = 0; i < n; ++i) {
        int src = adj[start + i];                 // wave-uniform -> broadcast
        float w = sc_src[src];
        float2 hv = *(const float2*)&h[src * D + j];
        acc.x += w * hv.x;
        acc.y += w * hv.y;
    }
    const float s = sc_dst[node];
    float2 o = *(float2*)&out[node * D + j];
    o.x += s * acc.x;
    o.y += s * acc.y;
    *(float2*)&out[node * D + j] = o;
}

extern "C" void kernel_launch(void* const* d_in, const int* in_sizes, int n_in,
                              void* d_out, int out_size, void* d_ws, size_t ws_size,
                              hipStream_t stream) {
    const float* x     = (const float*)d_in[0];
    const int*   edges = (const int*)d_in[1];      // [2, E]: row then col
    const float* W_src = (const float*)d_in[2];
    const float* b_src = (const float*)d_in[3];
    const float* W_dst = (const float*)d_in[4];
    const float* b_dst = (const float*)d_in[5];
    float* out = (float*)d_out;

    const int* row = edges;
    const int* col = edges + N_EDGES;

    // ---- workspace layout (33.6 MB total) ----
    float* h        = (float*)d_ws;                       // 6.4M floats
    float* sc_row   = h + (size_t)N_NODES * D;            // 50k floats
    float* sc_col   = sc_row + N_NODES;                   // 50k floats
    int*   ptr_row  = (int*)(sc_col + N_NODES);           // 50k ints
    int*   ptr_col  = ptr_row + N_NODES;                  // 50k ints
    int*   deg_row  = ptr_col + N_NODES;                  // 50k ints (zeroed)
    int*   deg_col  = deg_row + N_NODES;                  // 50k ints (zeroed)
    int*   fill_row = deg_col + N_NODES;                  // 50k ints (zeroed)
    int*   fill_col = fill_row + N_NODES;                 // 50k ints (zeroed)
    int*   adj_fwd  = fill_col + N_NODES;                 // 800k ints
    int*   adj_bwd  = adj_fwd + N_EDGES;                  // 800k ints

    (void)hipMemsetAsync(deg_row, 0, 4 * (size_t)N_NODES * sizeof(int), stream);

    const int gE = (N_EDGES + 255) / 256;
    const int gN = (N_NODES + 255) / 256;
    const int gT = (N_NODES + 31) / 32;              // gemm tiles
    const int gB = (N_NODES * 32) / 256;             // bias (exact)
    const int gG = N_NODES / 4;                      // gather (exact: 12500)

    k_degree<<<gE, 256, 0, stream>>>(row, col, deg_row, deg_col);
    k_dinv<<<gN, 256, 0, stream>>>(deg_row, deg_col, sc_row, sc_col);
    k_scan<<<2, 1024, 0, stream>>>(deg_row, ptr_row, deg_col, ptr_col);
    k_fill<<<gE, 256, 0, stream>>>(row, col, ptr_row, ptr_col,
                                   fill_row, fill_col, adj_fwd, adj_bwd);

    k_bias<<<gB, 256, 0, stream>>>(b_src, b_dst, out);

    // forward: dst=row, src=col
    k_gemm<<<gT, 256, 0, stream>>>(x, W_src, h);
    k_gather<<<gG, 256, 0, stream>>>(ptr_row, deg_row, adj_fwd, sc_row, sc_col, h, out);

    // backward: dst=col, src=row
    k_gemm<<<gT, 256, 0, stream>>>(x, W_dst, h);
    k_gather<<<gG, 256, 0, stream>>>(ptr_col, deg_col, adj_bwd, sc_col, sc_row, h, out);
}